// Round 10
// baseline (388.259 us; speedup 1.0000x reference)
//
#include <hip/hip_runtime.h>
#include <hip/hip_cooperative_groups.h>

namespace cg = cooperative_groups;

// MPS classifier, MI355X gfx950. Round 16: SINGLE COOPERATIVE KERNEL.
// r15 verified: main loop 191us (10 variants bracket 186-210; all knobs
// null), total 262 with ~71us outside the main dispatch (repack kernel +
// launch gap; actual repack memory work is only ~12us). Fix: fuse repack
// into the main kernel. 256 WGs x 512 thr are exactly co-resident
// (1 WG/CU, 87KB LDS) -> hipLaunchCooperativeKernel + grid.sync() legal.
// Phase A: each thread converts 1 fwd + 1 bwd repack unit (verbatim unit
// math, idx = global tid). Phase B: per-WG feature map (wsB-independent,
// overlaps repack tail). threadfence + grid.sync, then r15 main verbatim.

typedef _Float16 v8h __attribute__((ext_vector_type(8)));
typedef _Float16 h2  __attribute__((ext_vector_type(2)));
typedef float    v4f __attribute__((ext_vector_type(4)));

#define PI_HALF 1.5707963267948966f
#define SITE_U4 4096                 // uint4 per site: 2 planes * 32 frags * 64
#define TOFF_U4 (127*4096)           // bwd (transposed) half base, in uint4

union U4H8 { uint4 u; v8h h; };

__device__ __forceinline__ v4f mfma16h(uint4 a, uint4 b, v4f c){
  U4H8 ua, ub; ua.u = a; ub.u = b;
  return __builtin_amdgcn_mfma_f32_16x16x32_f16(ua.h, ub.h, c, 0, 0, 0);
}
__device__ __forceinline__ unsigned pack2h(float lo, float hi){
  h2 p; p[0] = (_Float16)lo; p[1] = (_Float16)hi;
  return __builtin_bit_cast(unsigned, p);
}
__device__ __forceinline__ unsigned short f16b(float v){
  return __builtin_bit_cast(unsigned short, (_Float16)v);
}

// ---------------------------------------------------------------------------
// Repack units (fp32 mid [254][128][2][128] -> fp16 frags), r15 math verbatim.
// fwd unit u (0..130047): sites 0..126, B-op frags [site][d][kt4][nt8][64]:
//   (lane,j) = mid[site][k=32kt+8(lane>>4)+j][d][n=16nt+(lane&15)]
// bwd unit u (0..130047): sites 127..253, A-op-T frags at TOFF
//   [srel][d][am8][kt4][64]: (lane,j) = mid[site][m=16am+(lane&15)][d][k=...]
// ---------------------------------------------------------------------------
__device__ __forceinline__ void repack_fwd_unit(int idx, const float* __restrict__ mid,
                                                unsigned short* __restrict__ wsB){
  int lg   = idx & 15;
  int nt   = (idx >> 4) & 7;
  int kt   = (idx >> 7) & 3;
  int d    = (idx >> 9) & 1;
  int site = idx >> 10;            // 0..126
  int q    = lg >> 2;
  int n0   = 16*nt + 4*(lg & 3);
  const float* src = mid + ((size_t)(site*128 + 32*kt + 8*q)*2 + d)*128 + n0;
  float V[8][4];
  #pragma unroll
  for (int j = 0; j < 8; ++j){
    float4 a = *(const float4*)(src + (size_t)j*256);
    V[j][0]=a.x; V[j][1]=a.y; V[j][2]=a.z; V[j][3]=a.w;
  }
  uint4* dst = (uint4*)wsB + ((((size_t)site*2 + d)*4 + kt)*8 + nt)*64
             + 16*q + 4*(lg & 3);
  #pragma unroll
  for (int t = 0; t < 4; ++t){
    uint4 o;
    o.x = pack2h(V[0][t], V[1][t]);
    o.y = pack2h(V[2][t], V[3][t]);
    o.z = pack2h(V[4][t], V[5][t]);
    o.w = pack2h(V[6][t], V[7][t]);
    dst[t] = o;
  }
}
__device__ __forceinline__ void repack_bwd_unit(int idx, const float* __restrict__ mid,
                                                unsigned short* __restrict__ wsB){
  int lg   = idx & 15;
  int kt   = (idx >> 4) & 3;
  int am   = (idx >> 6) & 7;
  int d    = (idx >> 9) & 1;
  int srel = idx >> 10;            // 0..126
  int site = 127 + srel;
  int q    = lg >> 2;
  int m0   = 16*am + 4*(lg & 3);
  int k0   = 32*kt + 8*q;
  uint4* dst = (uint4*)wsB + TOFF_U4
             + ((((size_t)srel*2 + d)*8 + am)*4 + kt)*64 + 16*q + 4*(lg & 3);
  #pragma unroll
  for (int mp = 0; mp < 4; ++mp){
    const float* src = mid + ((size_t)((site*128 + m0 + mp)*2) + d)*128 + k0;
    float4 a = *(const float4*)(src);
    float4 b = *(const float4*)(src + 4);
    uint4 o;
    o.x = pack2h(a.x, a.y);
    o.y = pack2h(a.z, a.w);
    o.z = pack2h(b.x, b.y);
    o.w = pack2h(b.z, b.w);
    dst[mp] = o;
  }
}

// ---------------------------------------------------------------------------
// Fused cooperative kernel: repack -> feature map -> grid sync -> r15 main.
// 256 WGs x 512 threads, 32 rows/WG, 1 WG/CU. Waves 0-3 fwd / 4-7 bwd.
// Slot swizzle: phys = S ^ ((S>>3)&7) on write and read.
// ---------------------------------------------------------------------------
__global__ __launch_bounds__(512, 2) void mps_fused(
    const float* __restrict__ x,               // [8192][256]
    const float* __restrict__ first,           // [2][128]
    unsigned short* __restrict__ wsBv,         // ws: fp16 frags (16.6 MB)
    const float* __restrict__ lastw,           // [128][2]
    const float* __restrict__ wlin,            // [10]
    const float* __restrict__ blin,            // [10]
    float* __restrict__ out,                   // [8192][10]
    const float* __restrict__ mid)             // [254][128][2][128]
{
  __shared__ unsigned phiT[256*36];        // 36 KB
  __shared__ unsigned Af[2*2*4*64*4];      // 16 KB  [buf][mt][kt][slot][word]
  __shared__ unsigned Rf[2*4*2*64*4];      // 16 KB  [buf][kt][nt][slot][word]
  __shared__ float Rcomb[128*33];          // 16.9 KB
  __shared__ float scal[32];

  const int tid  = threadIdx.x;
  const int gblk = blockIdx.x;
  const int w    = tid >> 6;               // 0..3 fwd, 4..7 bwd
  const int lane = tid & 63;
  const int r    = lane & 15;
  const int q    = lane >> 4;
  const int rh   = r >> 3;
  const int rowbase = gblk * 32;
  const int physL = lane ^ ((lane >> 3) & 7);

  // ---- Phase A: repack (each thread: one fwd unit + one bwd unit) ----
  {
    const int u = gblk * 512 + tid;        // 0..131071; units 0..130047
    if (u < 130048){
      repack_fwd_unit(u, mid, wsBv);
      repack_bwd_unit(u, mid, wsBv);
    }
  }

  // ---- Phase B: feature map -> packed f16 (cos,sin) table (wsB-independent) ----
  {
    const int row = tid >> 4;              // 0..31
    const int c0  = (tid & 15) * 16;       // 16-site chunk
    const float4* xp = (const float4*)(x + (size_t)(rowbase + row) * 256 + c0);
    float xv[16];
    float vmin = 3.0e38f, vmax = -3.0e38f;
    #pragma unroll
    for (int c = 0; c < 4; ++c){
      float4 u = xp[c];
      xv[c*4+0] = u.x; xv[c*4+1] = u.y; xv[c*4+2] = u.z; xv[c*4+3] = u.w;
      vmin = fminf(vmin, fminf(fminf(u.x,u.y), fminf(u.z,u.w)));
      vmax = fmaxf(vmax, fmaxf(fmaxf(u.x,u.y), fmaxf(u.z,u.w)));
    }
    #pragma unroll
    for (int m = 1; m < 16; m <<= 1){
      vmin = fminf(vmin, __shfl_xor(vmin, m));
      vmax = fmaxf(vmax, __shfl_xor(vmax, m));
    }
    const float sc = PI_HALF / (vmax - vmin + 1e-6f);
    #pragma unroll
    for (int j = 0; j < 16; ++j){
      float a = (xv[j] - vmin) * sc;
      phiT[(c0 + j)*36 + row] = pack2h(__cosf(a), __sinf(a));
    }
  }

  // ---- all WGs' repack writes visible before any WG reads wsB ----
  __threadfence();
  cg::this_grid().sync();

  // ---- Initial B prefetch (step 0): fwd site 0, bwd srel 126 (site 253) ----
  uint4 B0[16], B1[16];
  if (w < 4){
    const uint4* bp = (const uint4*)wsBv;
    #pragma unroll
    for (int d = 0; d < 2; ++d)
      #pragma unroll
      for (int kt = 0; kt < 4; ++kt)
        #pragma unroll
        for (int nb = 0; nb < 2; ++nb)
          B0[(d*4+kt)*2+nb] = bp[(size_t)((d*4 + kt)*8 + 2*w + nb)*64 + lane];
  } else {
    const int ww = w - 4;
    const uint4* bp = (const uint4*)wsBv + TOFF_U4 + (size_t)126 * SITE_U4;
    #pragma unroll
    for (int d = 0; d < 2; ++d)
      #pragma unroll
      for (int mtl = 0; mtl < 2; ++mtl)
        #pragma unroll
        for (int kt = 0; kt < 4; ++kt)
          B0[(d*2+mtl)*4+kt] = bp[(size_t)((d*8 + 2*ww + mtl)*4 + kt)*64 + lane];
  }

  // ---- State init (buf 0) ----
  if (w < 4){
    // left_1[b][l] = c0(b)*first[0][l] + s0(b)*first[1][l]; wave w: kt=w
    float f0[8], f1[8];
    #pragma unroll
    for (int j = 0; j < 8; ++j){
      int l = 32*w + 8*q + j;
      f0[j] = first[l]; f1[j] = first[128 + l];
    }
    #pragma unroll
    for (int mt = 0; mt < 2; ++mt){
      h2 ph0 = __builtin_bit_cast(h2, phiT[0*36 + 16*mt + r]);
      const float c0 = (float)ph0[0], s0 = (float)ph0[1];
      uint4 o;
      o.x = pack2h(f0[0]*c0 + f1[0]*s0, f0[1]*c0 + f1[1]*s0);
      o.y = pack2h(f0[2]*c0 + f1[2]*s0, f0[3]*c0 + f1[3]*s0);
      o.z = pack2h(f0[4]*c0 + f1[4]*s0, f0[5]*c0 + f1[5]*s0);
      o.w = pack2h(f0[6]*c0 + f1[6]*s0, f0[7]*c0 + f1[7]*s0);
      *(uint4*)&Af[((mt*4 + w)*64 + physL)*4] = o;
    }
  } else {
    // R_end[k][b] = lastw[k][0]*c255(b) + lastw[k][1]*s255(b); wave ww: kt=ww
    const int ww = w - 4;
    float g0[8], g1[8];
    #pragma unroll
    for (int j = 0; j < 8; ++j){
      int rr = 32*ww + 8*q + j;
      float2 gg = *(const float2*)(lastw + 2*rr);
      g0[j] = gg.x; g1[j] = gg.y;
    }
    #pragma unroll
    for (int nt = 0; nt < 2; ++nt){
      h2 p5 = __builtin_bit_cast(h2, phiT[255*36 + 16*nt + r]);
      const float cb = (float)p5[0], sb = (float)p5[1];
      uint4 o;
      o.x = pack2h(g0[0]*cb + g1[0]*sb, g0[1]*cb + g1[1]*sb);
      o.y = pack2h(g0[2]*cb + g1[2]*sb, g0[3]*cb + g1[3]*sb);
      o.z = pack2h(g0[4]*cb + g1[4]*sb, g0[5]*cb + g1[5]*sb);
      o.w = pack2h(g0[6]*cb + g1[6]*sb, g0[7]*cb + g1[7]*sb);
      *(uint4*)&Rf[((ww*2 + nt)*64 + physL)*4] = o;
    }
  }

  // ---- Step body: fwd consumes mid[t], phi(t+1); bwd mid[253-t], phi(254-t) ----
  auto body = [&](int t, uint4 (&Fc)[16], uint4 (&Fn)[16]){
    __syncthreads();   // state frags for step t visible; prev-buf reads done
    float vf[2][2][4]; // fwd final values (only live at t==126)

    if (w < 4){
      // prefetch fwd B for step t+1
      {
        const int soff = (t < 126) ? (t + 1) : 0;
        const uint4* bp = (const uint4*)wsBv + (size_t)soff * SITE_U4;
        #pragma unroll
        for (int d = 0; d < 2; ++d)
          #pragma unroll
          for (int kt = 0; kt < 4; ++kt)
            #pragma unroll
            for (int nb = 0; nb < 2; ++nb)
              Fn[(d*4+kt)*2+nb] = bp[(size_t)((d*4 + kt)*8 + 2*w + nb)*64 + lane];
      }
      v4f ac0[2][2] = {};   // [mt][nb], plane 0
      v4f ac1[2][2] = {};   // plane 1
      const unsigned* Ab = &Af[(t & 1) * 2048];
      #pragma unroll
      for (int kt = 0; kt < 4; ++kt){
        uint4 a0 = *(const uint4*)&Ab[((0*4 + kt)*64 + physL)*4];
        uint4 a1 = *(const uint4*)&Ab[((1*4 + kt)*64 + physL)*4];
        #pragma unroll
        for (int nb = 0; nb < 2; ++nb){
          ac0[0][nb] = mfma16h(a0, Fc[(0*4+kt)*2+nb], ac0[0][nb]);
          ac0[1][nb] = mfma16h(a1, Fc[(0*4+kt)*2+nb], ac0[1][nb]);
          ac1[0][nb] = mfma16h(a0, Fc[(1*4+kt)*2+nb], ac1[0][nb]);
          ac1[1][nb] = mfma16h(a1, Fc[(1*4+kt)*2+nb], ac1[1][nb]);
        }
      }
      if (t < 126){
        // left'[b][l]: b=16mt+4q+reg, l=32w+16nb+r -> Af[(t+1)&1], kt=w
        unsigned short* Wb = (unsigned short*)&Af[((t+1) & 1) * 2048];
        #pragma unroll
        for (int mt = 0; mt < 2; ++mt){
          uint4 phiu = *(const uint4*)&phiT[(t+1)*36 + 16*mt + 4*q];
          const unsigned pr[4] = {phiu.x, phiu.y, phiu.z, phiu.w};
          #pragma unroll
          for (int nb = 0; nb < 2; ++nb){
            const int S0 = 32*nb + 16*rh + 4*q;
            const int X  = 4*nb + 2*rh + (q >> 1);
            #pragma unroll
            for (int reg = 0; reg < 4; ++reg){
              h2 ph = __builtin_bit_cast(h2, pr[reg]);
              float v = (float)ph[0]*ac0[mt][nb][reg]
                      + (float)ph[1]*ac1[mt][nb][reg];
              Wb[((mt*4 + w)*64 + ((S0 + reg) ^ X))*8 + (r & 7)] = f16b(v);
            }
          }
        }
      } else {
        // final fwd: vf = left_128 (phi(127) applied), held in registers
        #pragma unroll
        for (int mt = 0; mt < 2; ++mt){
          uint4 phiu = *(const uint4*)&phiT[127*36 + 16*mt + 4*q];
          const unsigned pr[4] = {phiu.x, phiu.y, phiu.z, phiu.w};
          #pragma unroll
          for (int nb = 0; nb < 2; ++nb)
            #pragma unroll
            for (int reg = 0; reg < 4; ++reg){
              h2 ph = __builtin_bit_cast(h2, pr[reg]);
              vf[mt][nb][reg] = (float)ph[0]*ac0[mt][nb][reg]
                              + (float)ph[1]*ac1[mt][nb][reg];
            }
        }
      }
    } else {
      const int ww = w - 4;
      // prefetch bwd A (transposed frags) for step t+1
      {
        const int srel = (t < 126) ? (125 - t) : 0;
        const uint4* bp = (const uint4*)wsBv + TOFF_U4 + (size_t)srel * SITE_U4;
        #pragma unroll
        for (int d = 0; d < 2; ++d)
          #pragma unroll
          for (int mtl = 0; mtl < 2; ++mtl)
            #pragma unroll
            for (int kt = 0; kt < 4; ++kt)
              Fn[(d*2+mtl)*4+kt] = bp[(size_t)((d*8 + 2*ww + mtl)*4 + kt)*64 + lane];
      }
      v4f ac0[2][2] = {};   // [mtl][nt], plane 0
      v4f ac1[2][2] = {};   // plane 1
      const unsigned* Rb = &Rf[(t & 1) * 2048];
      #pragma unroll
      for (int kt = 0; kt < 4; ++kt){
        uint4 b0 = *(const uint4*)&Rb[((kt*2 + 0)*64 + physL)*4];
        uint4 b1 = *(const uint4*)&Rb[((kt*2 + 1)*64 + physL)*4];
        #pragma unroll
        for (int mtl = 0; mtl < 2; ++mtl){
          ac0[mtl][0] = mfma16h(Fc[(0*2+mtl)*4+kt], b0, ac0[mtl][0]);
          ac0[mtl][1] = mfma16h(Fc[(0*2+mtl)*4+kt], b1, ac0[mtl][1]);
          ac1[mtl][0] = mfma16h(Fc[(1*2+mtl)*4+kt], b0, ac1[mtl][0]);
          ac1[mtl][1] = mfma16h(Fc[(1*2+mtl)*4+kt], b1, ac1[mtl][1]);
        }
      }
      const int ps = 254 - t;
      if (t < 126){
        // R'[k=l][b]: l=32ww+16mtl+4q+reg, b=16nb+r -> Rf[(t+1)&1], kt=ww
        unsigned short* Wr = (unsigned short*)&Rf[((t+1) & 1) * 2048];
        #pragma unroll
        for (int nb = 0; nb < 2; ++nb){
          h2 ph = __builtin_bit_cast(h2, phiT[ps*36 + 16*nb + r]);
          const float cb = (float)ph[0], sb = (float)ph[1];
          #pragma unroll
          for (int mtl = 0; mtl < 2; ++mtl){
            const int S0 = 32*mtl + 16*(q >> 1) + r;
            const int phys = S0 ^ ((S0 >> 3) & 7);
            #pragma unroll
            for (int reg = 0; reg < 4; ++reg){
              float v = cb*ac0[mtl][nb][reg] + sb*ac1[mtl][nb][reg];
              Wr[((ww*2 + nb)*64 + phys)*8 + ((4*q + reg) & 7)] = f16b(v);
            }
          }
        }
      } else {
        // final bwd: R_127 -> Rcomb[l][b]
        #pragma unroll
        for (int nb = 0; nb < 2; ++nb){
          h2 ph = __builtin_bit_cast(h2, phiT[ps*36 + 16*nb + r]);
          const float cb = (float)ph[0], sb = (float)ph[1];
          #pragma unroll
          for (int mtl = 0; mtl < 2; ++mtl)
            #pragma unroll
            for (int reg = 0; reg < 4; ++reg){
              float v = cb*ac0[mtl][nb][reg] + sb*ac1[mtl][nb][reg];
              int l = 32*ww + 16*mtl + 4*q + reg;
              Rcomb[l*33 + 16*nb + r] = v;
            }
        }
      }
    }

    if (t == 126){
      if (tid < 32) scal[tid] = 0.0f;
      __syncthreads();   // Rcomb + scal ready
      if (w < 4){
        float p[2][4] = {};
        #pragma unroll
        for (int mt = 0; mt < 2; ++mt)
          #pragma unroll
          for (int nb = 0; nb < 2; ++nb){
            const int l = 32*w + 16*nb + r;
            #pragma unroll
            for (int reg = 0; reg < 4; ++reg)
              p[mt][reg] += vf[mt][nb][reg] * Rcomb[l*33 + 16*mt + 4*q + reg];
          }
        #pragma unroll
        for (int m = 1; m < 16; m <<= 1)
          #pragma unroll
          for (int mt = 0; mt < 2; ++mt)
            #pragma unroll
            for (int reg = 0; reg < 4; ++reg)
              p[mt][reg] += __shfl_xor(p[mt][reg], m);
        if (r == 0){
          #pragma unroll
          for (int mt = 0; mt < 2; ++mt)
            #pragma unroll
            for (int reg = 0; reg < 4; ++reg)
              atomicAdd(&scal[16*mt + 4*q + reg], p[mt][reg]);
        }
      }
      __syncthreads();
      for (int t2 = tid; t2 < 320; t2 += 512){
        int bb = t2 / 10, o = t2 - bb*10;
        out[(size_t)(rowbase + bb)*10 + o] = scal[bb]*wlin[o] + blin[o];
      }
    }
  };

  #pragma unroll 1
  for (int t = 0; t < 126; t += 2){
    body(t,     B0, B1);
    body(t + 1, B1, B0);
  }
  body(126, B0, B1);
}

extern "C" void kernel_launch(void* const* d_in, const int* in_sizes, int n_in,
                              void* d_out, int out_size, void* d_ws, size_t ws_size,
                              hipStream_t stream){
  (void)in_sizes; (void)n_in; (void)out_size; (void)ws_size;
  const float* x     = (const float*)d_in[0];
  const float* first = (const float*)d_in[1];
  const float* mid   = (const float*)d_in[2];
  const float* lastw = (const float*)d_in[3];
  const float* wlin  = (const float*)d_in[4];
  const float* blin  = (const float*)d_in[5];
  float* o            = (float*)d_out;
  unsigned short* wsB = (unsigned short*)d_ws;   // 16.6 MB fp16 fragments

  void* args[] = { (void*)&x, (void*)&first, (void*)&wsB, (void*)&lastw,
                   (void*)&wlin, (void*)&blin, (void*)&o, (void*)&mid };
  hipLaunchCooperativeKernel(reinterpret_cast<void*>(mps_fused),
                             dim3(256), dim3(512), args, 0, stream);
}